// Round 4
// baseline (269.787 us; speedup 1.0000x reference)
//
#include <hip/hip_runtime.h>
#include <hip/hip_bf16.h>

#define HID   256
#define NP    100
#define KSZ   3
#define NPKS  (NP*KSZ)        // 300
#define K2PAD 384             // 3 * 128 (t*128 + c layout)
#define N1T   24              // 384/16 N-tiles of GEMM1
#define PC    104             // kT pitch in bf16 elems (c-dim)
#define KTROWS 258            // l = -1 .. 256
#define KT_ELEMS (KTROWS*PC + 80)   // 26912 shorts = 53824 B -> 3 blocks/CU
#define WS_PITCH 40
#define WS_ELEMS (112*WS_PITCH)

using bf16x8 = __attribute__((ext_vector_type(8))) short;
using f32x4  = __attribute__((ext_vector_type(4))) float;

__device__ __forceinline__ short f2bf(float x) {
    __hip_bfloat16 h = __float2bfloat16(x);
    return __builtin_bit_cast(short, h);
}

// ---------- prep: W_lin -> bf16 B-fragment-ordered W2f, permuted bias ----------
__global__ void dyconv_prep(const float* __restrict__ W_lin,
                            const float* __restrict__ b_lin,
                            short* __restrict__ W2f,   // [8 kt][24 nt][64 lane][8] bf16
                            float* __restrict__ b2f) { // [384]
    int gid = blockIdx.x * blockDim.x + threadIdx.x;   // 0..12287
    int lane = gid & 63;
    int ent  = gid >> 6;            // kt*24 + nt
    int kt = ent / N1T;
    int nt = ent % N1T;
    int n  = nt*16 + (lane & 15);   // K2 index of GEMM2 = t*128 + c
    int t  = n >> 7;
    int c  = n & 127;
    int k0 = kt*32 + ((lane >> 4) << 3);
    short vals[8];
#pragma unroll
    for (int j = 0; j < 8; ++j) {
        float v = (c < NP) ? W_lin[(k0 + j) * NPKS + c*KSZ + t] : 0.0f;
        vals[j] = f2bf(v);
    }
    *reinterpret_cast<bf16x8*>(&W2f[(size_t)gid * 8]) =
        *reinterpret_cast<bf16x8*>(vals);
    if (gid < K2PAD) {
        int tt = gid >> 7, cc = gid & 127;
        b2f[gid] = (cc < NP) ? b_lin[cc*KSZ + tt] : 0.0f;
    }
}

// ---------- kernel A: w = f @ W_lin + b, written bf16 in B-kernel fragment layout ----------
__global__ __launch_bounds__(256)
void dyconv_gemm1(const float* __restrict__ f, const short* __restrict__ W2f,
                  const float* __restrict__ b2f, short* __restrict__ w2, int Mrows) {
    __shared__ short smem[64*392];     // 50176 B
    const int tid = threadIdx.x, wave = tid>>6, lane = tid&63, lg = lane>>4, li = lane&15;
    const int r0 = blockIdx.x * 64;

    int myr = r0 + wave*16 + li; if (myr > Mrows-1) myr = Mrows-1;
    const float* frow = f + (size_t)myr * HID + lg*8;
    bf16x8 a1[8];
#pragma unroll
    for (int kt = 0; kt < 8; ++kt) {
        float4 u = *reinterpret_cast<const float4*>(frow + kt*32);
        float4 v = *reinterpret_cast<const float4*>(frow + kt*32 + 4);
        short tmp[8] = {f2bf(u.x),f2bf(u.y),f2bf(u.z),f2bf(u.w),
                        f2bf(v.x),f2bf(v.y),f2bf(v.z),f2bf(v.w)};
        a1[kt] = *reinterpret_cast<bf16x8*>(tmp);
    }

    f32x4 acc[24];
#pragma unroll
    for (int i = 0; i < 24; ++i) acc[i] = (f32x4){0.f,0.f,0.f,0.f};

#pragma unroll
    for (int ch = 0; ch < 6; ++ch) {
#pragma unroll
        for (int i0 = 0; i0 < 8; ++i0) {
            int i = i0*256 + tid;               // 0..2047
            int kt = i >> 8, rem = i & 255;
            *reinterpret_cast<int4*>(&smem[(size_t)i*8]) =
                *reinterpret_cast<const int4*>(&W2f[((size_t)(kt*N1T + ch*4)*64 + rem)*8]);
        }
        __syncthreads();
#pragma unroll
        for (int ntl = 0; ntl < 4; ++ntl) {
#pragma unroll
            for (int kt = 0; kt < 8; ++kt) {
                bf16x8 bfr = *reinterpret_cast<const bf16x8*>(
                    &smem[((kt*4 + ntl)*64 + lane)*8]);
                acc[ch*4 + ntl] = __builtin_amdgcn_mfma_f32_16x16x32_bf16(
                    a1[kt], bfr, acc[ch*4 + ntl], 0,0,0);
            }
        }
        __syncthreads();
    }

    // epilogue: bias + bf16 -> LDS [64][392], then coalesced 64B stores in w2 layout
#pragma unroll
    for (int nt = 0; nt < 24; ++nt) {
        int col = nt*16 + li;
        float bias = b2f[col];
#pragma unroll
        for (int ro = 0; ro < 4; ++ro) {
            int row = wave*16 + lg*4 + ro;
            smem[row*392 + col] = f2bf(acc[nt][ro] + bias);
        }
    }
    __syncthreads();
    for (int i = tid; i < 64*12; i += 256) {
        int row = i / 12, kc = i % 12;
        int r = r0 + row;
        if (r < Mrows) {
            int b = r / NP, p = r % NP;
            const int4* src = reinterpret_cast<const int4*>(&smem[row*392 + kc*32]);
            int4* dst = reinterpret_cast<int4*>(&w2[(((size_t)b*12 + kc)*NP + p)*32]);
            dst[0]=src[0]; dst[1]=src[1]; dst[2]=src[2]; dst[3]=src[3];
        }
    }
}

// ---------- kernel B: conv (GEMM2) + LayerNorm, one block per batch, no inner barriers ----------
__global__ __launch_bounds__(256)
void dyconv_conv(const float* __restrict__ k, const short* __restrict__ w2,
                 const float* __restrict__ gamma, const float* __restrict__ beta,
                 float* __restrict__ out) {
    __shared__ short kT[KT_ELEMS];     // kT[l+1][c], zero-padded; LN overlay after
    float* lnbuf = reinterpret_cast<float*>(kT);

    const int b = blockIdx.x, tid = threadIdx.x;
    const int wave = tid>>6, lane = tid&63, lg = lane>>4, li = lane&15;

    for (int i = tid; i < KT_ELEMS/8; i += 256)
        reinterpret_cast<int4*>(kT)[i] = make_int4(0,0,0,0);
    __syncthreads();

    const float* kb = k + (size_t)b * (NP*HID);
    for (int idx4 = tid; idx4 < NP*HID/4; idx4 += 256) {
        float4 v = reinterpret_cast<const float4*>(kb)[idx4];
        int c = idx4 >> 6, l0 = (idx4 & 63)*4;
        kT[(l0+1)*PC + c] = f2bf(v.x);
        kT[(l0+2)*PC + c] = f2bf(v.y);
        kT[(l0+3)*PC + c] = f2bf(v.z);
        kT[(l0+4)*PC + c] = f2bf(v.w);
    }

    f32x4 acc2[7][4];
#pragma unroll
    for (int mt = 0; mt < 7; ++mt)
#pragma unroll
        for (int j = 0; j < 4; ++j) acc2[mt][j] = (f32x4){0.f,0.f,0.f,0.f};

    __syncthreads();   // kT ready; no more barriers until epilogue

    const short* wb = w2 + (size_t)b * 12 * NP * 32;
    bf16x8 a2[7], a2n[7];
#pragma unroll
    for (int mt = 0; mt < 7; ++mt) {
        int p = mt*16 + li; if (p > NP-1) p = NP-1;
        a2[mt] = *reinterpret_cast<const bf16x8*>(&wb[((size_t)p)*32 + lg*8]);
    }

    for (int kc = 0; kc < 12; ++kc) {
        if (kc < 11) {
#pragma unroll
            for (int mt = 0; mt < 7; ++mt) {
                int p = mt*16 + li; if (p > NP-1) p = NP-1;
                a2n[mt] = *reinterpret_cast<const bf16x8*>(
                    &wb[((size_t)(kc+1)*NP + p)*32 + lg*8]);
            }
        }
        int k2 = kc*32 + lg*8;
        int t  = k2 >> 7, c = k2 & 127;
#pragma unroll
        for (int j = 0; j < 4; ++j) {
            int l = (wave*4 + j)*16 + li;
            bf16x8 b2v = *reinterpret_cast<const bf16x8*>(&kT[(l + t)*PC + c]);
#pragma unroll
            for (int mt = 0; mt < 7; ++mt)
                acc2[mt][j] = __builtin_amdgcn_mfma_f32_16x16x32_bf16(
                    a2[mt], b2v, acc2[mt][j], 0,0,0);
        }
#pragma unroll
        for (int mt = 0; mt < 7; ++mt) a2[mt] = a2n[mt];
    }

    __syncthreads();   // kT reads done; overlay LN buffers

    float* psum  = lnbuf;            // [4][112][2]
    float* mrstd = lnbuf + 4*112*2;  // [112][2]
#pragma unroll
    for (int mt = 0; mt < 7; ++mt) {
#pragma unroll
        for (int r = 0; r < 4; ++r) {
            float s1 = 0.f, s2 = 0.f;
#pragma unroll
            for (int j = 0; j < 4; ++j) {
                float v = acc2[mt][j][r];
                s1 += v; s2 += v*v;
            }
#pragma unroll
            for (int m = 1; m < 16; m <<= 1) {
                s1 += __shfl_xor(s1, m, 64);
                s2 += __shfl_xor(s2, m, 64);
            }
            if (li == 0) {
                int p = mt*16 + lg*4 + r;
                psum[(wave*112 + p)*2 + 0] = s1;
                psum[(wave*112 + p)*2 + 1] = s2;
            }
        }
    }
    __syncthreads();
    if (tid < 112) {
        float S1 = 0.f, S2 = 0.f;
#pragma unroll
        for (int w2i = 0; w2i < 4; ++w2i) {
            S1 += psum[(w2i*112 + tid)*2 + 0];
            S2 += psum[(w2i*112 + tid)*2 + 1];
        }
        float mean = S1 * (1.0f/HID);
        float var  = S2 * (1.0f/HID) - mean*mean;
        mrstd[tid*2 + 0] = mean;
        mrstd[tid*2 + 1] = rsqrtf(var + 1e-5f);
    }
    __syncthreads();

    float* ob = out + (size_t)b * (NP*HID);
#pragma unroll
    for (int j = 0; j < 4; ++j) {
        int l = (wave*4 + j)*16 + li;
        float g  = gamma[l];
        float be = beta[l];
#pragma unroll
        for (int mt = 0; mt < 7; ++mt) {
#pragma unroll
            for (int r = 0; r < 4; ++r) {
                int p = mt*16 + lg*4 + r;
                if (p < NP) {
                    float mean = mrstd[p*2], rstd = mrstd[p*2 + 1];
                    ob[p*HID + l] = (acc2[mt][j][r] - mean)*rstd*g + be;
                }
            }
        }
    }
}

// ---------- fallback fused kernel (proven R1 path) if ws too small ----------
__global__ __launch_bounds__(256)
void dyconv_main(const float* __restrict__ f, const float* __restrict__ k,
                 const short* __restrict__ W2f, const float* __restrict__ b2f,
                 const float* __restrict__ gamma, const float* __restrict__ beta,
                 float* __restrict__ out) {
    __shared__ short kT[KT_ELEMS];
    __shared__ short wS[WS_ELEMS];
    float* lnbuf = reinterpret_cast<float*>(wS);
    const int b = blockIdx.x, tid = threadIdx.x;
    const int wave = tid>>6, lane = tid&63, lg = lane>>4, li = lane&15;
    for (int i = tid; i < KT_ELEMS/8; i += 256)
        reinterpret_cast<int4*>(kT)[i] = make_int4(0,0,0,0);
    __syncthreads();
    const float* kb = k + (size_t)b * (NP*HID);
    for (int idx = tid; idx < NP*HID; idx += 256) {
        int c = idx >> 8, l = idx & 255;
        kT[(l+1)*PC + c] = f2bf(kb[idx]);
    }
    const float* fb = f + (size_t)b * (NP*HID);
    const int nmy = (wave < 3) ? 2 : 1;
    bf16x8 a1[2][8];
#pragma unroll
    for (int mi = 0; mi < 2; ++mi) {
        if (mi < nmy) {
            int mt = wave + 4*mi;
            int p  = mt*16 + li; if (p > NP-1) p = NP-1;
            const float* rowp = fb + (size_t)p * HID + lg*8;
#pragma unroll
            for (int kt = 0; kt < 8; ++kt) {
                float4 u = *reinterpret_cast<const float4*>(rowp + kt*32);
                float4 v = *reinterpret_cast<const float4*>(rowp + kt*32 + 4);
                short tmp[8] = {f2bf(u.x),f2bf(u.y),f2bf(u.z),f2bf(u.w),
                                f2bf(v.x),f2bf(v.y),f2bf(v.z),f2bf(v.w)};
                a1[mi][kt] = *reinterpret_cast<bf16x8*>(tmp);
            }
        }
    }
    f32x4 acc2[7][4];
#pragma unroll
    for (int mt = 0; mt < 7; ++mt)
#pragma unroll
        for (int j = 0; j < 4; ++j) acc2[mt][j] = (f32x4){0.f,0.f,0.f,0.f};
    __syncthreads();
    for (int kc = 0; kc < 12; ++kc) {
        f32x4 acc1[2][2];
#pragma unroll
        for (int mi = 0; mi < 2; ++mi)
#pragma unroll
            for (int n = 0; n < 2; ++n) acc1[mi][n] = (f32x4){0.f,0.f,0.f,0.f};
#pragma unroll
        for (int kt = 0; kt < 8; ++kt) {
            bf16x8 b1[2];
#pragma unroll
            for (int ntl = 0; ntl < 2; ++ntl) {
                int NT = kc*2 + ntl;
                b1[ntl] = *reinterpret_cast<const bf16x8*>(
                    &W2f[(((size_t)kt*N1T + NT)*64 + lane)*8]);
            }
#pragma unroll
            for (int mi = 0; mi < 2; ++mi) {
                if (mi < nmy) {
                    acc1[mi][0] = __builtin_amdgcn_mfma_f32_16x16x32_bf16(
                        a1[mi][kt], b1[0], acc1[mi][0], 0,0,0);
                    acc1[mi][1] = __builtin_amdgcn_mfma_f32_16x16x32_bf16(
                        a1[mi][kt], b1[1], acc1[mi][1], 0,0,0);
                }
            }
        }
#pragma unroll
        for (int mi = 0; mi < 2; ++mi) {
            if (mi < nmy) {
                int mt = wave + 4*mi;
#pragma unroll
                for (int ntl = 0; ntl < 2; ++ntl) {
                    int col  = ntl*16 + li;
                    float bias = b2f[kc*32 + col];
#pragma unroll
                    for (int r = 0; r < 4; ++r) {
                        int row = mt*16 + lg*4 + r;
                        wS[row*WS_PITCH + col] = f2bf(acc1[mi][ntl][r] + bias);
                    }
                }
            }
        }
        __syncthreads();
        bf16x8 a2[7];
#pragma unroll
        for (int mt = 0; mt < 7; ++mt)
            a2[mt] = *reinterpret_cast<const bf16x8*>(&wS[(mt*16 + li)*WS_PITCH + lg*8]);
        int k2 = kc*32 + lg*8;
        int t  = k2 >> 7, c = k2 & 127;
#pragma unroll
        for (int j = 0; j < 4; ++j) {
            int l = (wave*4 + j)*16 + li;
            bf16x8 b2v = *reinterpret_cast<const bf16x8*>(&kT[(l + t)*PC + c]);
#pragma unroll
            for (int mt = 0; mt < 7; ++mt)
                acc2[mt][j] = __builtin_amdgcn_mfma_f32_16x16x32_bf16(
                    a2[mt], b2v, acc2[mt][j], 0,0,0);
        }
        __syncthreads();
    }
    float* psum  = lnbuf;
    float* mrstd = lnbuf + 4*112*2;
#pragma unroll
    for (int mt = 0; mt < 7; ++mt) {
#pragma unroll
        for (int r = 0; r < 4; ++r) {
            float s1 = 0.f, s2 = 0.f;
#pragma unroll
            for (int j = 0; j < 4; ++j) {
                float v = acc2[mt][j][r];
                s1 += v; s2 += v*v;
            }
#pragma unroll
            for (int m = 1; m < 16; m <<= 1) {
                s1 += __shfl_xor(s1, m, 64);
                s2 += __shfl_xor(s2, m, 64);
            }
            if (li == 0) {
                int p = mt*16 + lg*4 + r;
                psum[(wave*112 + p)*2 + 0] = s1;
                psum[(wave*112 + p)*2 + 1] = s2;
            }
        }
    }
    __syncthreads();
    if (tid < 112) {
        float S1 = 0.f, S2 = 0.f;
#pragma unroll
        for (int w2i = 0; w2i < 4; ++w2i) {
            S1 += psum[(w2i*112 + tid)*2 + 0];
            S2 += psum[(w2i*112 + tid)*2 + 1];
        }
        float mean = S1 * (1.0f/HID);
        float var  = S2 * (1.0f/HID) - mean*mean;
        mrstd[tid*2 + 0] = mean;
        mrstd[tid*2 + 1] = rsqrtf(var + 1e-5f);
    }
    __syncthreads();
    float* ob = out + (size_t)b * (NP*HID);
#pragma unroll
    for (int j = 0; j < 4; ++j) {
        int l = (wave*4 + j)*16 + li;
        float g  = gamma[l];
        float be = beta[l];
#pragma unroll
        for (int mt = 0; mt < 7; ++mt) {
#pragma unroll
            for (int r = 0; r < 4; ++r) {
                int p = mt*16 + lg*4 + r;
                if (p < NP) {
                    float mean = mrstd[p*2], rstd = mrstd[p*2 + 1];
                    ob[p*HID + l] = (acc2[mt][j][r] - mean)*rstd*g + be;
                }
            }
        }
    }
}

extern "C" void kernel_launch(void* const* d_in, const int* in_sizes, int n_in,
                              void* d_out, int out_size, void* d_ws, size_t ws_size,
                              hipStream_t stream) {
    const float* f     = (const float*)d_in[0];
    const float* k     = (const float*)d_in[1];
    const float* W_lin = (const float*)d_in[2];
    const float* b_lin = (const float*)d_in[3];
    const float* gamma = (const float*)d_in[4];
    const float* beta  = (const float*)d_in[5];
    float* out = (float*)d_out;

    short* W2f = (short*)d_ws;                                   // 196608 B
    float* b2f = (float*)((char*)d_ws + 196608);                 // 1536 B
    const size_t off_w2 = 198144;
    const int B = in_sizes[0] / (NP*HID);
    const int Mrows = B * NP;
    const size_t need = off_w2 + (size_t)B * 12 * NP * 32 * 2;   // ~78.8 MB @ B=1024

    dyconv_prep<<<48, 256, 0, stream>>>(W_lin, b_lin, W2f, b2f);

    if (ws_size >= need) {
        short* w2 = (short*)((char*)d_ws + off_w2);
        dyconv_gemm1<<<(Mrows + 63)/64, 256, 0, stream>>>(f, W2f, b2f, w2, Mrows);
        dyconv_conv<<<B, 256, 0, stream>>>(k, w2, gamma, beta, out);
    } else {
        dyconv_main<<<B, 256, 0, stream>>>(f, k, W2f, b2f, gamma, beta, out);
    }
}

// Round 5
// 241.221 us; speedup vs baseline: 1.1184x; 1.1184x over previous
//
#include <hip/hip_runtime.h>
#include <hip/hip_bf16.h>

#define HID   256
#define NP    100
#define KSZ   3
#define NPKS  (NP*KSZ)        // 300
#define K2PAD 384             // 3 * 128 (t*128 + c layout)
#define N1T   24              // 384/16 N-tiles of GEMM1
#define PC    104             // kT pitch in bf16 elems (c-dim)
#define KTROWS 258            // l = -1 .. 256
#define KT_ELEMS (KTROWS*PC + 80)   // 26912 shorts = 53824 B
#define WS_PITCH 40
#define WS_ELEMS (112*WS_PITCH)

using bf16x8 = __attribute__((ext_vector_type(8))) short;
using f32x4  = __attribute__((ext_vector_type(4))) float;

__device__ __forceinline__ short f2bf(float x) {
    __hip_bfloat16 h = __float2bfloat16(x);
    return __builtin_bit_cast(short, h);
}

// ---------- prep: W_lin -> bf16 B-fragment-ordered W2f, permuted bias ----------
__global__ void dyconv_prep(const float* __restrict__ W_lin,
                            const float* __restrict__ b_lin,
                            short* __restrict__ W2f,   // [8 kt][24 nt][64 lane][8] bf16
                            float* __restrict__ b2f) { // [384]
    int gid = blockIdx.x * blockDim.x + threadIdx.x;   // 0..12287
    int lane = gid & 63;
    int ent  = gid >> 6;            // kt*24 + nt
    int kt = ent / N1T;
    int nt = ent % N1T;
    int n  = nt*16 + (lane & 15);   // K2 index of GEMM2 = t*128 + c
    int t  = n >> 7;
    int c  = n & 127;
    int k0 = kt*32 + ((lane >> 4) << 3);
    short vals[8];
#pragma unroll
    for (int j = 0; j < 8; ++j) {
        float v = (c < NP) ? W_lin[(k0 + j) * NPKS + c*KSZ + t] : 0.0f;
        vals[j] = f2bf(v);
    }
    *reinterpret_cast<bf16x8*>(&W2f[(size_t)gid * 8]) =
        *reinterpret_cast<bf16x8*>(vals);
    if (gid < K2PAD) {
        int tt = gid >> 7, cc = gid & 127;
        b2f[gid] = (cc < NP) ? b_lin[cc*KSZ + tt] : 0.0f;
    }
}

// ---------- kernel A v2: no LDS, no barriers; B-fragments direct from global ----------
__global__ __launch_bounds__(256)
void dyconv_gemm1(const float* __restrict__ f, const short* __restrict__ W2f,
                  const float* __restrict__ b2f, short* __restrict__ w2, int Mrows) {
    const int tid = threadIdx.x, wave = tid>>6, lane = tid&63, lg = lane>>4, li = lane&15;
    const int r0 = blockIdx.x * 64;

    // f fragments (read once, fp32->bf16)
    int myr = r0 + wave*16 + li; if (myr > Mrows-1) myr = Mrows-1;
    const float* frow = f + (size_t)myr * HID + lg*8;
    bf16x8 a1[8];
#pragma unroll
    for (int kt = 0; kt < 8; ++kt) {
        float4 u = *reinterpret_cast<const float4*>(frow + kt*32);
        float4 v = *reinterpret_cast<const float4*>(frow + kt*32 + 4);
        short tmp[8] = {f2bf(u.x),f2bf(u.y),f2bf(u.z),f2bf(u.w),
                        f2bf(v.x),f2bf(v.y),f2bf(v.z),f2bf(v.w)};
        a1[kt] = *reinterpret_cast<bf16x8*>(tmp);
    }

    f32x4 acc[24];
#pragma unroll
    for (int i = 0; i < 24; ++i) acc[i] = (f32x4){0.f,0.f,0.f,0.f};

    const short* Wl = W2f + (size_t)lane * 8;   // frag(kt,nt) at + (kt*24+nt)*64*8
    bf16x8 F0[8], F1[8], F2[8];
#define LDW(FB, NT) { _Pragma("unroll") for (int kt = 0; kt < 8; ++kt) \
    FB[kt] = *reinterpret_cast<const bf16x8*>(Wl + ((size_t)(kt*N1T + (NT)) << 9)); }
#define MM(FB, NT) { _Pragma("unroll") for (int kt = 0; kt < 8; ++kt) \
    acc[NT] = __builtin_amdgcn_mfma_f32_16x16x32_bf16(a1[kt], FB[kt], acc[NT], 0,0,0); }
    LDW(F0,0)  LDW(F1,1)
    LDW(F2,2)  MM(F0,0)
    LDW(F0,3)  MM(F1,1)
    LDW(F1,4)  MM(F2,2)
    LDW(F2,5)  MM(F0,3)
    LDW(F0,6)  MM(F1,4)
    LDW(F1,7)  MM(F2,5)
    LDW(F2,8)  MM(F0,6)
    LDW(F0,9)  MM(F1,7)
    LDW(F1,10) MM(F2,8)
    LDW(F2,11) MM(F0,9)
    LDW(F0,12) MM(F1,10)
    LDW(F1,13) MM(F2,11)
    LDW(F2,14) MM(F0,12)
    LDW(F0,15) MM(F1,13)
    LDW(F1,16) MM(F2,14)
    LDW(F2,17) MM(F0,15)
    LDW(F0,18) MM(F1,16)
    LDW(F1,19) MM(F2,17)
    LDW(F2,20) MM(F0,18)
    LDW(F0,21) MM(F1,19)
    LDW(F1,22) MM(F2,20)
    LDW(F2,23) MM(F0,21)
    MM(F1,22)  MM(F2,23)
#undef LDW
#undef MM

    // epilogue: direct 2B stores in w2 layout (nt-pairs fill 64B sectors; L2 merges)
    const int prow0 = wave*16 + lg*4;
#pragma unroll
    for (int r = 0; r < 4; ++r) {
        int gr = r0 + prow0 + r;
        if (gr < Mrows) {
            int bb = gr / NP, p = gr % NP;
            short* wrow = w2 + ((size_t)bb*12*NP + p)*32;
#pragma unroll
            for (int nt = 0; nt < 24; ++nt) {
                float bias = b2f[nt*16 + li];
                wrow[(size_t)(nt>>1)*NP*32 + (nt&1)*16 + li] = f2bf(acc[nt][r] + bias);
            }
        }
    }
}

// ---------- kernel B v2: conv (GEMM2) + LayerNorm, barrier-free main loop ----------
__global__ __launch_bounds__(256)
void dyconv_conv(const float* __restrict__ k, const short* __restrict__ w2,
                 const float* __restrict__ gamma, const float* __restrict__ beta,
                 float* __restrict__ out) {
    __shared__ short kT[KT_ELEMS];     // kT[l+1][c] bf16; LN overlay after
    float* lnbuf = reinterpret_cast<float*>(kT);

    const int b = blockIdx.x, tid = threadIdx.x;
    const int wave = tid>>6, lane = tid&63, lg = lane>>4, li = lane&15;

    // zero only pad rows 0 & 257, and the tail guard (rest written exactly once below)
    if (tid < 26) {
        *reinterpret_cast<ulong*>(&kT[0*PC + tid*4])   = 0ul;
        *reinterpret_cast<ulong*>(&kT[257*PC + tid*4]) = 0ul;
    }
    if (tid < 20)
        *reinterpret_cast<ulong*>(&kT[258*PC + tid*4]) = 0ul;

    // stage k[b] transposed: unit = lgr*26 + quad; thread reads 4 rows x 4 l's,
    // writes 4 x ds_write_b64 (4 consecutive c) -> c-contiguous lanes, ~2-way conflicts
    const float* kb = k + (size_t)b * (NP*HID);
    for (int u = tid; u < 64*26; u += 256) {
        int quad = u % 26, lgr = u / 26;
        int c = quad*4, l0 = lgr*4;
        float4 row[4];
#pragma unroll
        for (int cc = 0; cc < 4; ++cc)
            row[cc] = (c + cc < NP)
                ? *reinterpret_cast<const float4*>(kb + (size_t)(c+cc)*HID + l0)
                : make_float4(0.f,0.f,0.f,0.f);
#pragma unroll
        for (int ll = 0; ll < 4; ++ll) {
            float e0 = (ll==0)?row[0].x:(ll==1)?row[0].y:(ll==2)?row[0].z:row[0].w;
            float e1 = (ll==0)?row[1].x:(ll==1)?row[1].y:(ll==2)?row[1].z:row[1].w;
            float e2 = (ll==0)?row[2].x:(ll==1)?row[2].y:(ll==2)?row[2].z:row[2].w;
            float e3 = (ll==0)?row[3].x:(ll==1)?row[3].y:(ll==2)?row[3].z:row[3].w;
            short s[4] = {f2bf(e0), f2bf(e1), f2bf(e2), f2bf(e3)};
            *reinterpret_cast<ulong*>(&kT[(l0+ll+1)*PC + c]) =
                *reinterpret_cast<ulong*>(s);
        }
    }

    f32x4 acc2[7][4];
#pragma unroll
    for (int mt = 0; mt < 7; ++mt)
#pragma unroll
        for (int j = 0; j < 4; ++j) acc2[mt][j] = (f32x4){0.f,0.f,0.f,0.f};

    __syncthreads();   // kT ready; no more barriers until epilogue

    const short* wb = w2 + (size_t)b * 12 * NP * 32;
    bf16x8 F0[7], F1[7], F2[7];
#define LOADW(FB, KC) { _Pragma("unroll") for (int mt = 0; mt < 7; ++mt) { \
    int p = mt*16 + li; if (p > NP-1) p = NP-1; \
    FB[mt] = *reinterpret_cast<const bf16x8*>(&wb[((size_t)(KC)*NP + p)*32 + lg*8]); } }
#define CHUNK(FB, KC) { int k2 = (KC)*32 + lg*8; int t = k2>>7, c = k2&127; \
    _Pragma("unroll") for (int j = 0; j < 4; ++j) { \
        int l = (wave*4 + j)*16 + li; \
        bf16x8 b2v = *reinterpret_cast<const bf16x8*>(&kT[(l + t)*PC + c]); \
        _Pragma("unroll") for (int mt = 0; mt < 7; ++mt) \
            acc2[mt][j] = __builtin_amdgcn_mfma_f32_16x16x32_bf16(FB[mt], b2v, acc2[mt][j], 0,0,0); } }
    LOADW(F0,0)  LOADW(F1,1)
    LOADW(F2,2)  CHUNK(F0,0)
    LOADW(F0,3)  CHUNK(F1,1)
    LOADW(F1,4)  CHUNK(F2,2)
    LOADW(F2,5)  CHUNK(F0,3)
    LOADW(F0,6)  CHUNK(F1,4)
    LOADW(F1,7)  CHUNK(F2,5)
    LOADW(F2,8)  CHUNK(F0,6)
    LOADW(F0,9)  CHUNK(F1,7)
    LOADW(F1,10) CHUNK(F2,8)
    LOADW(F2,11) CHUNK(F0,9)
    CHUNK(F1,10) CHUNK(F2,11)
#undef LOADW
#undef CHUNK

    __syncthreads();   // kT reads done; overlay LN buffers

    float* psum  = lnbuf;            // [4][112][2]
    float* mrstd = lnbuf + 4*112*2;  // [112][2]
#pragma unroll
    for (int mt = 0; mt < 7; ++mt) {
#pragma unroll
        for (int r = 0; r < 4; ++r) {
            float s1 = 0.f, s2 = 0.f;
#pragma unroll
            for (int j = 0; j < 4; ++j) {
                float v = acc2[mt][j][r];
                s1 += v; s2 += v*v;
            }
#pragma unroll
            for (int m = 1; m < 16; m <<= 1) {
                s1 += __shfl_xor(s1, m, 64);
                s2 += __shfl_xor(s2, m, 64);
            }
            if (li == 0) {
                int p = mt*16 + lg*4 + r;
                psum[(wave*112 + p)*2 + 0] = s1;
                psum[(wave*112 + p)*2 + 1] = s2;
            }
        }
    }
    __syncthreads();
    if (tid < 112) {
        float S1 = 0.f, S2 = 0.f;
#pragma unroll
        for (int w2i = 0; w2i < 4; ++w2i) {
            S1 += psum[(w2i*112 + tid)*2 + 0];
            S2 += psum[(w2i*112 + tid)*2 + 1];
        }
        float mean = S1 * (1.0f/HID);
        float var  = S2 * (1.0f/HID) - mean*mean;
        mrstd[tid*2 + 0] = mean;
        mrstd[tid*2 + 1] = rsqrtf(var + 1e-5f);
    }
    __syncthreads();

    float* ob = out + (size_t)b * (NP*HID);
#pragma unroll
    for (int j = 0; j < 4; ++j) {
        int l = (wave*4 + j)*16 + li;
        float g  = gamma[l];
        float be = beta[l];
#pragma unroll
        for (int mt = 0; mt < 7; ++mt) {
#pragma unroll
            for (int r = 0; r < 4; ++r) {
                int p = mt*16 + lg*4 + r;
                if (p < NP) {
                    float mean = mrstd[p*2], rstd = mrstd[p*2 + 1];
                    ob[p*HID + l] = (acc2[mt][j][r] - mean)*rstd*g + be;
                }
            }
        }
    }
}

// ---------- fallback fused kernel (proven R1 path) if ws too small ----------
__global__ __launch_bounds__(256)
void dyconv_main(const float* __restrict__ f, const float* __restrict__ k,
                 const short* __restrict__ W2f, const float* __restrict__ b2f,
                 const float* __restrict__ gamma, const float* __restrict__ beta,
                 float* __restrict__ out) {
    __shared__ short kT[KT_ELEMS];
    __shared__ short wS[WS_ELEMS];
    float* lnbuf = reinterpret_cast<float*>(wS);
    const int b = blockIdx.x, tid = threadIdx.x;
    const int wave = tid>>6, lane = tid&63, lg = lane>>4, li = lane&15;
    for (int i = tid; i < KT_ELEMS/8; i += 256)
        reinterpret_cast<int4*>(kT)[i] = make_int4(0,0,0,0);
    __syncthreads();
    const float* kb = k + (size_t)b * (NP*HID);
    for (int idx = tid; idx < NP*HID; idx += 256) {
        int c = idx >> 8, l = idx & 255;
        kT[(l+1)*PC + c] = f2bf(kb[idx]);
    }
    const float* fb = f + (size_t)b * (NP*HID);
    const int nmy = (wave < 3) ? 2 : 1;
    bf16x8 a1[2][8];
#pragma unroll
    for (int mi = 0; mi < 2; ++mi) {
        if (mi < nmy) {
            int mt = wave + 4*mi;
            int p  = mt*16 + li; if (p > NP-1) p = NP-1;
            const float* rowp = fb + (size_t)p * HID + lg*8;
#pragma unroll
            for (int kt = 0; kt < 8; ++kt) {
                float4 u = *reinterpret_cast<const float4*>(rowp + kt*32);
                float4 v = *reinterpret_cast<const float4*>(rowp + kt*32 + 4);
                short tmp[8] = {f2bf(u.x),f2bf(u.y),f2bf(u.z),f2bf(u.w),
                                f2bf(v.x),f2bf(v.y),f2bf(v.z),f2bf(v.w)};
                a1[mi][kt] = *reinterpret_cast<bf16x8*>(tmp);
            }
        }
    }
    f32x4 acc2[7][4];
#pragma unroll
    for (int mt = 0; mt < 7; ++mt)
#pragma unroll
        for (int j = 0; j < 4; ++j) acc2[mt][j] = (f32x4){0.f,0.f,0.f,0.f};
    __syncthreads();
    for (int kc = 0; kc < 12; ++kc) {
        f32x4 acc1[2][2];
#pragma unroll
        for (int mi = 0; mi < 2; ++mi)
#pragma unroll
            for (int n = 0; n < 2; ++n) acc1[mi][n] = (f32x4){0.f,0.f,0.f,0.f};
#pragma unroll
        for (int kt = 0; kt < 8; ++kt) {
            bf16x8 b1[2];
#pragma unroll
            for (int ntl = 0; ntl < 2; ++ntl) {
                int NT = kc*2 + ntl;
                b1[ntl] = *reinterpret_cast<const bf16x8*>(
                    &W2f[(((size_t)kt*N1T + NT)*64 + lane)*8]);
            }
#pragma unroll
            for (int mi = 0; mi < 2; ++mi) {
                if (mi < nmy) {
                    acc1[mi][0] = __builtin_amdgcn_mfma_f32_16x16x32_bf16(
                        a1[mi][kt], b1[0], acc1[mi][0], 0,0,0);
                    acc1[mi][1] = __builtin_amdgcn_mfma_f32_16x16x32_bf16(
                        a1[mi][kt], b1[1], acc1[mi][1], 0,0,0);
                }
            }
        }
#pragma unroll
        for (int mi = 0; mi < 2; ++mi) {
            if (mi < nmy) {
                int mt = wave + 4*mi;
#pragma unroll
                for (int ntl = 0; ntl < 2; ++ntl) {
                    int col  = ntl*16 + li;
                    float bias = b2f[kc*32 + col];
#pragma unroll
                    for (int r = 0; r < 4; ++r) {
                        int row = mt*16 + lg*4 + r;
                        wS[row*WS_PITCH + col] = f2bf(acc1[mi][ntl][r] + bias);
                    }
                }
            }
        }
        __syncthreads();
        bf16x8 a2[7];
#pragma unroll
        for (int mt = 0; mt < 7; ++mt)
            a2[mt] = *reinterpret_cast<const bf16x8*>(&wS[(mt*16 + li)*WS_PITCH + lg*8]);
        int k2 = kc*32 + lg*8;
        int t  = k2 >> 7, c = k2 & 127;
#pragma unroll
        for (int j = 0; j < 4; ++j) {
            int l = (wave*4 + j)*16 + li;
            bf16x8 b2v = *reinterpret_cast<const bf16x8*>(&kT[(l + t)*PC + c]);
#pragma unroll
            for (int mt = 0; mt < 7; ++mt)
                acc2[mt][j] = __builtin_amdgcn_mfma_f32_16x16x32_bf16(
                    a2[mt], b2v, acc2[mt][j], 0,0,0);
        }
        __syncthreads();
    }
    float* psum  = lnbuf;
    float* mrstd = lnbuf + 4*112*2;
#pragma unroll
    for (int mt = 0; mt < 7; ++mt) {
#pragma unroll
        for (int r = 0; r < 4; ++r) {
            float s1 = 0.f, s2 = 0.f;
#pragma unroll
            for (int j = 0; j < 4; ++j) {
                float v = acc2[mt][j][r];
                s1 += v; s2 += v*v;
            }
#pragma unroll
            for (int m = 1; m < 16; m <<= 1) {
                s1 += __shfl_xor(s1, m, 64);
                s2 += __shfl_xor(s2, m, 64);
            }
            if (li == 0) {
                int p = mt*16 + lg*4 + r;
                psum[(wave*112 + p)*2 + 0] = s1;
                psum[(wave*112 + p)*2 + 1] = s2;
            }
        }
    }
    __syncthreads();
    if (tid < 112) {
        float S1 = 0.f, S2 = 0.f;
#pragma unroll
        for (int w2i = 0; w2i < 4; ++w2i) {
            S1 += psum[(w2i*112 + tid)*2 + 0];
            S2 += psum[(w2i*112 + tid)*2 + 1];
        }
        float mean = S1 * (1.0f/HID);
        float var  = S2 * (1.0f/HID) - mean*mean;
        mrstd[tid*2 + 0] = mean;
        mrstd[tid*2 + 1] = rsqrtf(var + 1e-5f);
    }
    __syncthreads();
    float* ob = out + (size_t)b * (NP*HID);
#pragma unroll
    for (int j = 0; j < 4; ++j) {
        int l = (wave*4 + j)*16 + li;
        float g  = gamma[l];
        float be = beta[l];
#pragma unroll
        for (int mt = 0; mt < 7; ++mt) {
#pragma unroll
            for (int r = 0; r < 4; ++r) {
                int p = mt*16 + lg*4 + r;
                if (p < NP) {
                    float mean = mrstd[p*2], rstd = mrstd[p*2 + 1];
                    ob[p*HID + l] = (acc2[mt][j][r] - mean)*rstd*g + be;
                }
            }
        }
    }
}

extern "C" void kernel_launch(void* const* d_in, const int* in_sizes, int n_in,
                              void* d_out, int out_size, void* d_ws, size_t ws_size,
                              hipStream_t stream) {
    const float* f     = (const float*)d_in[0];
    const float* k     = (const float*)d_in[1];
    const float* W_lin = (const float*)d_in[2];
    const float* b_lin = (const float*)d_in[3];
    const float* gamma = (const float*)d_in[4];
    const float* beta  = (const float*)d_in[5];
    float* out = (float*)d_out;

    short* W2f = (short*)d_ws;                                   // 196608 B
    float* b2f = (float*)((char*)d_ws + 196608);                 // 1536 B
    const size_t off_w2 = 198144;
    const int B = in_sizes[0] / (NP*HID);
    const int Mrows = B * NP;
    const size_t need = off_w2 + (size_t)B * 12 * NP * 32 * 2;   // ~78.8 MB @ B=1024

    dyconv_prep<<<48, 256, 0, stream>>>(W_lin, b_lin, W2f, b2f);

    if (ws_size >= need) {
        short* w2 = (short*)((char*)d_ws + off_w2);
        dyconv_gemm1<<<(Mrows + 63)/64, 256, 0, stream>>>(f, W2f, b2f, w2, Mrows);
        dyconv_conv<<<B, 256, 0, stream>>>(k, w2, gamma, beta, out);
    } else {
        dyconv_main<<<B, 256, 0, stream>>>(f, k, W2f, b2f, gamma, beta, out);
    }
}

// Round 6
// 202.217 us; speedup vs baseline: 1.3341x; 1.1929x over previous
//
#include <hip/hip_runtime.h>
#include <hip/hip_bf16.h>

#define HID   256
#define NP    100
#define KSZ   3
#define NPKS  (NP*KSZ)        // 300
#define K2PAD 384             // 3 * 128 (t*128 + c layout)
#define N1T   24              // 384/16 N-tiles of GEMM1
#define PC    104             // kT pitch in bf16 elems (c-dim)
#define KTROWS 258            // l = -1 .. 256
#define KT_ELEMS (KTROWS*PC + 80)   // 26912 shorts = 53824 B
#define WS_PITCH 40
#define WS_ELEMS (112*WS_PITCH)

using bf16x8 = __attribute__((ext_vector_type(8))) short;
using f32x4  = __attribute__((ext_vector_type(4))) float;

__device__ __forceinline__ short f2bf(float x) {
    __hip_bfloat16 h = __float2bfloat16(x);
    return __builtin_bit_cast(short, h);
}

// ---------- prep: W_lin -> bf16 B-fragment-ordered W2f, permuted bias ----------
__global__ void dyconv_prep(const float* __restrict__ W_lin,
                            const float* __restrict__ b_lin,
                            short* __restrict__ W2f,   // [8 kt][24 nt][64 lane][8] bf16
                            float* __restrict__ b2f) { // [384]
    int gid = blockIdx.x * blockDim.x + threadIdx.x;   // 0..12287
    int lane = gid & 63;
    int ent  = gid >> 6;            // kt*24 + nt
    int kt = ent / N1T;
    int nt = ent % N1T;
    int n  = nt*16 + (lane & 15);   // K2 index of GEMM2 = t*128 + c
    int t  = n >> 7;
    int c  = n & 127;
    int k0 = kt*32 + ((lane >> 4) << 3);
    short vals[8];
#pragma unroll
    for (int j = 0; j < 8; ++j) {
        float v = (c < NP) ? W_lin[(k0 + j) * NPKS + c*KSZ + t] : 0.0f;
        vals[j] = f2bf(v);
    }
    *reinterpret_cast<bf16x8*>(&W2f[(size_t)gid * 8]) =
        *reinterpret_cast<bf16x8*>(vals);
    if (gid < K2PAD) {
        int tt = gid >> 7, cc = gid & 127;
        b2f[gid] = (cc < NP) ? b_lin[cc*KSZ + tt] : 0.0f;
    }
}

// ---------- kernel A v3: no LDS/barriers, 2 half-passes over N (acc=48) for 3 waves/SIMD ----------
__global__ __launch_bounds__(256, 3)
void dyconv_gemm1(const float* __restrict__ f, const short* __restrict__ W2f,
                  const float* __restrict__ b2f, short* __restrict__ w2, int Mrows) {
    const int tid = threadIdx.x, wave = tid>>6, lane = tid&63, lg = lane>>4, li = lane&15;
    const int r0 = blockIdx.x * 64;

    // f fragments (read once, reused by both halves)
    int myr = r0 + wave*16 + li; if (myr > Mrows-1) myr = Mrows-1;
    const float* frow = f + (size_t)myr * HID + lg*8;
    bf16x8 a1[8];
#pragma unroll
    for (int kt = 0; kt < 8; ++kt) {
        float4 u = *reinterpret_cast<const float4*>(frow + kt*32);
        float4 v = *reinterpret_cast<const float4*>(frow + kt*32 + 4);
        short tmp[8] = {f2bf(u.x),f2bf(u.y),f2bf(u.z),f2bf(u.w),
                        f2bf(v.x),f2bf(v.y),f2bf(v.z),f2bf(v.w)};
        a1[kt] = *reinterpret_cast<bf16x8*>(tmp);
    }

    const short* Wl = W2f + (size_t)lane * 8;   // frag(kt,nt) at + (kt*24+nt)*512
    const int prow0 = wave*16 + lg*4;

#pragma unroll 1
    for (int h = 0; h < 2; ++h) {
        const int nb = h*12;
        f32x4 acc[12];
#pragma unroll
        for (int i = 0; i < 12; ++i) acc[i] = (f32x4){0.f,0.f,0.f,0.f};

        bf16x8 F0[8], F1[8];
#define LDW(FB, NTL) { _Pragma("unroll") for (int kt = 0; kt < 8; ++kt) \
    FB[kt] = *reinterpret_cast<const bf16x8*>(Wl + ((size_t)(kt*N1T + nb + (NTL)) << 9)); }
#define MM(FB, NTL) { _Pragma("unroll") for (int kt = 0; kt < 8; ++kt) \
    acc[NTL] = __builtin_amdgcn_mfma_f32_16x16x32_bf16(a1[kt], FB[kt], acc[NTL], 0,0,0); }
        LDW(F0,0)  LDW(F1,1)
        MM(F0,0)   LDW(F0,2)
        MM(F1,1)   LDW(F1,3)
        MM(F0,2)   LDW(F0,4)
        MM(F1,3)   LDW(F1,5)
        MM(F0,4)   LDW(F0,6)
        MM(F1,5)   LDW(F1,7)
        MM(F0,6)   LDW(F0,8)
        MM(F1,7)   LDW(F1,9)
        MM(F0,8)   LDW(F0,10)
        MM(F1,9)   LDW(F1,11)
        MM(F0,10)  MM(F1,11)
#undef LDW
#undef MM

        // store this half's 12 N-tiles (2B stores; nt-pairs fill 64B sectors, L2 merges)
#pragma unroll
        for (int r = 0; r < 4; ++r) {
            int gr = r0 + prow0 + r;
            if (gr < Mrows) {
                int bb = gr / NP, p = gr % NP;
                short* wrow = w2 + ((size_t)bb*12*NP + p)*32;
#pragma unroll
                for (int ntl = 0; ntl < 12; ++ntl) {
                    int nt = nb + ntl;
                    float bias = b2f[nt*16 + li];
                    wrow[(size_t)(nt>>1)*NP*32 + (nt&1)*16 + li] = f2bf(acc[ntl][r] + bias);
                }
            }
        }
    }
}

// ---------- kernel B v3: conv (GEMM2) + LN; coalesced staging, pad-only zeroing,
// single-buffered compiler-pipelined loop under launch_bounds(256,3) ----------
__global__ __launch_bounds__(256, 3)
void dyconv_conv(const float* __restrict__ k, const short* __restrict__ w2,
                 const float* __restrict__ gamma, const float* __restrict__ beta,
                 float* __restrict__ out) {
    __shared__ short kT[KT_ELEMS];     // kT[l+1][c] bf16; LN overlay after
    float* lnbuf = reinterpret_cast<float*>(kT);

    const int b = blockIdx.x, tid = threadIdx.x;
    const int wave = tid>>6, lane = tid&63, lg = lane>>4, li = lane&15;

    // zero all NaN-reachable, never-written bytes:
    // pad rows 0 (l=-1) and 257 (l=256), c-strip [100,104) of every row, tail guard
    if (tid < 26) {
        *reinterpret_cast<unsigned long long*>(&kT[0*PC + tid*4])   = 0ull;
        *reinterpret_cast<unsigned long long*>(&kT[257*PC + tid*4]) = 0ull;
    }
    if (tid < 20)
        *reinterpret_cast<unsigned long long*>(&kT[KTROWS*PC + tid*4]) = 0ull;
    for (int r = tid; r < KTROWS; r += 256)
        *reinterpret_cast<unsigned long long*>(&kT[r*PC + 100]) = 0ull;

    // stage k[b] transposed (coalesced float4 reads; scalar ds_writes)
    const float* kb = k + (size_t)b * (NP*HID);
    for (int idx4 = tid; idx4 < NP*HID/4; idx4 += 256) {
        float4 v = reinterpret_cast<const float4*>(kb)[idx4];
        int c = idx4 >> 6, l0 = (idx4 & 63)*4;
        kT[(l0+1)*PC + c] = f2bf(v.x);
        kT[(l0+2)*PC + c] = f2bf(v.y);
        kT[(l0+3)*PC + c] = f2bf(v.z);
        kT[(l0+4)*PC + c] = f2bf(v.w);
    }

    f32x4 acc2[7][4];
#pragma unroll
    for (int mt = 0; mt < 7; ++mt)
#pragma unroll
        for (int j = 0; j < 4; ++j) acc2[mt][j] = (f32x4){0.f,0.f,0.f,0.f};

    __syncthreads();   // kT ready; no more barriers until epilogue

    const short* wb = w2 + (size_t)b * 12 * NP * 32;
#pragma unroll
    for (int kc = 0; kc < 12; ++kc) {
        bf16x8 a2[7];
#pragma unroll
        for (int mt = 0; mt < 7; ++mt) {
            int p = mt*16 + li; if (p > NP-1) p = NP-1;
            a2[mt] = *reinterpret_cast<const bf16x8*>(
                &wb[((size_t)kc*NP + p)*32 + lg*8]);
        }
        int k2 = kc*32 + lg*8;
        int t  = k2 >> 7, c = k2 & 127;
#pragma unroll
        for (int j = 0; j < 4; ++j) {
            int l = (wave*4 + j)*16 + li;
            bf16x8 b2v = *reinterpret_cast<const bf16x8*>(&kT[(l + t)*PC + c]);
#pragma unroll
            for (int mt = 0; mt < 7; ++mt)
                acc2[mt][j] = __builtin_amdgcn_mfma_f32_16x16x32_bf16(
                    a2[mt], b2v, acc2[mt][j], 0,0,0);
        }
    }

    __syncthreads();   // kT reads done; overlay LN buffers

    float* psum  = lnbuf;            // [4][112][2]
    float* mrstd = lnbuf + 4*112*2;  // [112][2]
#pragma unroll
    for (int mt = 0; mt < 7; ++mt) {
#pragma unroll
        for (int r = 0; r < 4; ++r) {
            float s1 = 0.f, s2 = 0.f;
#pragma unroll
            for (int j = 0; j < 4; ++j) {
                float v = acc2[mt][j][r];
                s1 += v; s2 += v*v;
            }
#pragma unroll
            for (int m = 1; m < 16; m <<= 1) {
                s1 += __shfl_xor(s1, m, 64);
                s2 += __shfl_xor(s2, m, 64);
            }
            if (li == 0) {
                int p = mt*16 + lg*4 + r;
                psum[(wave*112 + p)*2 + 0] = s1;
                psum[(wave*112 + p)*2 + 1] = s2;
            }
        }
    }
    __syncthreads();
    if (tid < 112) {
        float S1 = 0.f, S2 = 0.f;
#pragma unroll
        for (int w2i = 0; w2i < 4; ++w2i) {
            S1 += psum[(w2i*112 + tid)*2 + 0];
            S2 += psum[(w2i*112 + tid)*2 + 1];
        }
        float mean = S1 * (1.0f/HID);
        float var  = S2 * (1.0f/HID) - mean*mean;
        mrstd[tid*2 + 0] = mean;
        mrstd[tid*2 + 1] = rsqrtf(var + 1e-5f);
    }
    __syncthreads();

    float* ob = out + (size_t)b * (NP*HID);
#pragma unroll
    for (int j = 0; j < 4; ++j) {
        int l = (wave*4 + j)*16 + li;
        float g  = gamma[l];
        float be = beta[l];
#pragma unroll
        for (int mt = 0; mt < 7; ++mt) {
#pragma unroll
            for (int r = 0; r < 4; ++r) {
                int p = mt*16 + lg*4 + r;
                if (p < NP) {
                    float mean = mrstd[p*2], rstd = mrstd[p*2 + 1];
                    ob[p*HID + l] = (acc2[mt][j][r] - mean)*rstd*g + be;
                }
            }
        }
    }
}

// ---------- fallback fused kernel (proven R1 path) if ws too small ----------
__global__ __launch_bounds__(256)
void dyconv_main(const float* __restrict__ f, const float* __restrict__ k,
                 const short* __restrict__ W2f, const float* __restrict__ b2f,
                 const float* __restrict__ gamma, const float* __restrict__ beta,
                 float* __restrict__ out) {
    __shared__ short kT[KT_ELEMS];
    __shared__ short wS[WS_ELEMS];
    float* lnbuf = reinterpret_cast<float*>(wS);
    const int b = blockIdx.x, tid = threadIdx.x;
    const int wave = tid>>6, lane = tid&63, lg = lane>>4, li = lane&15;
    for (int i = tid; i < KT_ELEMS/8; i += 256)
        reinterpret_cast<int4*>(kT)[i] = make_int4(0,0,0,0);
    __syncthreads();
    const float* kb = k + (size_t)b * (NP*HID);
    for (int idx = tid; idx < NP*HID; idx += 256) {
        int c = idx >> 8, l = idx & 255;
        kT[(l+1)*PC + c] = f2bf(kb[idx]);
    }
    const float* fb = f + (size_t)b * (NP*HID);
    const int nmy = (wave < 3) ? 2 : 1;
    bf16x8 a1[2][8];
#pragma unroll
    for (int mi = 0; mi < 2; ++mi) {
        if (mi < nmy) {
            int mt = wave + 4*mi;
            int p  = mt*16 + li; if (p > NP-1) p = NP-1;
            const float* rowp = fb + (size_t)p * HID + lg*8;
#pragma unroll
            for (int kt = 0; kt < 8; ++kt) {
                float4 u = *reinterpret_cast<const float4*>(rowp + kt*32);
                float4 v = *reinterpret_cast<const float4*>(rowp + kt*32 + 4);
                short tmp[8] = {f2bf(u.x),f2bf(u.y),f2bf(u.z),f2bf(u.w),
                                f2bf(v.x),f2bf(v.y),f2bf(v.z),f2bf(v.w)};
                a1[mi][kt] = *reinterpret_cast<bf16x8*>(tmp);
            }
        }
    }
    f32x4 acc2[7][4];
#pragma unroll
    for (int mt = 0; mt < 7; ++mt)
#pragma unroll
        for (int j = 0; j < 4; ++j) acc2[mt][j] = (f32x4){0.f,0.f,0.f,0.f};
    __syncthreads();
    for (int kc = 0; kc < 12; ++kc) {
        f32x4 acc1[2][2];
#pragma unroll
        for (int mi = 0; mi < 2; ++mi)
#pragma unroll
            for (int n = 0; n < 2; ++n) acc1[mi][n] = (f32x4){0.f,0.f,0.f,0.f};
#pragma unroll
        for (int kt = 0; kt < 8; ++kt) {
            bf16x8 b1[2];
#pragma unroll
            for (int ntl = 0; ntl < 2; ++ntl) {
                int NT = kc*2 + ntl;
                b1[ntl] = *reinterpret_cast<const bf16x8*>(
                    &W2f[(((size_t)kt*N1T + NT)*64 + lane)*8]);
            }
#pragma unroll
            for (int mi = 0; mi < 2; ++mi) {
                if (mi < nmy) {
                    acc1[mi][0] = __builtin_amdgcn_mfma_f32_16x16x32_bf16(
                        a1[mi][kt], b1[0], acc1[mi][0], 0,0,0);
                    acc1[mi][1] = __builtin_amdgcn_mfma_f32_16x16x32_bf16(
                        a1[mi][kt], b1[1], acc1[mi][1], 0,0,0);
                }
            }
        }
#pragma unroll
        for (int mi = 0; mi < 2; ++mi) {
            if (mi < nmy) {
                int mt = wave + 4*mi;
#pragma unroll
                for (int ntl = 0; ntl < 2; ++ntl) {
                    int col  = ntl*16 + li;
                    float bias = b2f[kc*32 + col];
#pragma unroll
                    for (int r = 0; r < 4; ++r) {
                        int row = mt*16 + lg*4 + r;
                        wS[row*WS_PITCH + col] = f2bf(acc1[mi][ntl][r] + bias);
                    }
                }
            }
        }
        __syncthreads();
        bf16x8 a2[7];
#pragma unroll
        for (int mt = 0; mt < 7; ++mt)
            a2[mt] = *reinterpret_cast<const bf16x8*>(&wS[(mt*16 + li)*WS_PITCH + lg*8]);
        int k2 = kc*32 + lg*8;
        int t  = k2 >> 7, c = k2 & 127;
#pragma unroll
        for (int j = 0; j < 4; ++j) {
            int l = (wave*4 + j)*16 + li;
            bf16x8 b2v = *reinterpret_cast<const bf16x8*>(&kT[(l + t)*PC + c]);
#pragma unroll
            for (int mt = 0; mt < 7; ++mt)
                acc2[mt][j] = __builtin_amdgcn_mfma_f32_16x16x32_bf16(
                    a2[mt], b2v, acc2[mt][j], 0,0,0);
        }
        __syncthreads();
    }
    float* psum  = lnbuf;
    float* mrstd = lnbuf + 4*112*2;
#pragma unroll
    for (int mt = 0; mt < 7; ++mt) {
#pragma unroll
        for (int r = 0; r < 4; ++r) {
            float s1 = 0.f, s2 = 0.f;
#pragma unroll
            for (int j = 0; j < 4; ++j) {
                float v = acc2[mt][j][r];
                s1 += v; s2 += v*v;
            }
#pragma unroll
            for (int m = 1; m < 16; m <<= 1) {
                s1 += __shfl_xor(s1, m, 64);
                s2 += __shfl_xor(s2, m, 64);
            }
            if (li == 0) {
                int p = mt*16 + lg*4 + r;
                psum[(wave*112 + p)*2 + 0] = s1;
                psum[(wave*112 + p)*2 + 1] = s2;
            }
        }
    }
    __syncthreads();
    if (tid < 112) {
        float S1 = 0.f, S2 = 0.f;
#pragma unroll
        for (int w2i = 0; w2i < 4; ++w2i) {
            S1 += psum[(w2i*112 + tid)*2 + 0];
            S2 += psum[(w2i*112 + tid)*2 + 1];
        }
        float mean = S1 * (1.0f/HID);
        float var  = S2 * (1.0f/HID) - mean*mean;
        mrstd[tid*2 + 0] = mean;
        mrstd[tid*2 + 1] = rsqrtf(var + 1e-5f);
    }
    __syncthreads();
    float* ob = out + (size_t)b * (NP*HID);
#pragma unroll
    for (int j = 0; j < 4; ++j) {
        int l = (wave*4 + j)*16 + li;
        float g  = gamma[l];
        float be = beta[l];
#pragma unroll
        for (int mt = 0; mt < 7; ++mt) {
#pragma unroll
            for (int r = 0; r < 4; ++r) {
                int p = mt*16 + lg*4 + r;
                if (p < NP) {
                    float mean = mrstd[p*2], rstd = mrstd[p*2 + 1];
                    ob[p*HID + l] = (acc2[mt][j][r] - mean)*rstd*g + be;
                }
            }
        }
    }
}

extern "C" void kernel_launch(void* const* d_in, const int* in_sizes, int n_in,
                              void* d_out, int out_size, void* d_ws, size_t ws_size,
                              hipStream_t stream) {
    const float* f     = (const float*)d_in[0];
    const float* k     = (const float*)d_in[1];
    const float* W_lin = (const float*)d_in[2];
    const float* b_lin = (const float*)d_in[3];
    const float* gamma = (const float*)d_in[4];
    const float* beta  = (const float*)d_in[5];
    float* out = (float*)d_out;

    short* W2f = (short*)d_ws;                                   // 196608 B
    float* b2f = (float*)((char*)d_ws + 196608);                 // 1536 B
    const size_t off_w2 = 198144;
    const int B = in_sizes[0] / (NP*HID);
    const int Mrows = B * NP;
    const size_t need = off_w2 + (size_t)B * 12 * NP * 32 * 2;   // ~78.8 MB @ B=1024

    dyconv_prep<<<48, 256, 0, stream>>>(W_lin, b_lin, W2f, b2f);

    if (ws_size >= need) {
        short* w2 = (short*)((char*)d_ws + off_w2);
        dyconv_gemm1<<<(Mrows + 63)/64, 256, 0, stream>>>(f, W2f, b2f, w2, Mrows);
        dyconv_conv<<<B, 256, 0, stream>>>(k, w2, gamma, beta, out);
    } else {
        dyconv_main<<<B, 256, 0, stream>>>(f, k, W2f, b2f, gamma, beta, out);
    }
}

// Round 7
// 177.745 us; speedup vs baseline: 1.5178x; 1.1377x over previous
//
#include <hip/hip_runtime.h>
#include <hip/hip_bf16.h>

#define HID   256
#define NP    100
#define KSZ   3
#define NPKS  (NP*KSZ)        // 300
#define K2PAD 384             // 3 * 128 (t*128 + c layout)
#define N1T   24              // 384/16 N-tiles of GEMM1
#define PC    104             // kT pitch in bf16 elems (c-dim)
#define KTROWS 258            // l = -1 .. 256
#define KT_ELEMS (KTROWS*PC + 80)   // 26912 shorts = 53824 B (80-short guard for c>104 reads)
#define WS_PITCH 40
#define WS_ELEMS (112*WS_PITCH)

using bf16x8 = __attribute__((ext_vector_type(8))) short;
using f32x4  = __attribute__((ext_vector_type(4))) float;

__device__ __forceinline__ short f2bf(float x) {
    __hip_bfloat16 h = __float2bfloat16(x);
    return __builtin_bit_cast(short, h);
}

// ---------- prep: W_lin -> bf16 B-fragment-ordered W2f, permuted bias ----------
__global__ void dyconv_prep(const float* __restrict__ W_lin,
                            const float* __restrict__ b_lin,
                            short* __restrict__ W2f,   // [8 kt][24 nt][64 lane][8] bf16
                            float* __restrict__ b2f) { // [384]
    int gid = blockIdx.x * blockDim.x + threadIdx.x;   // 0..12287
    int lane = gid & 63;
    int ent  = gid >> 6;            // kt*24 + nt
    int kt = ent / N1T;
    int nt = ent % N1T;
    int n  = nt*16 + (lane & 15);   // K2 index of GEMM2 = t*128 + c
    int t  = n >> 7;
    int c  = n & 127;
    int k0 = kt*32 + ((lane >> 4) << 3);
    short vals[8];
#pragma unroll
    for (int j = 0; j < 8; ++j) {
        float v = (c < NP) ? W_lin[(k0 + j) * NPKS + c*KSZ + t] : 0.0f;
        vals[j] = f2bf(v);
    }
    *reinterpret_cast<bf16x8*>(&W2f[(size_t)gid * 8]) =
        *reinterpret_cast<bf16x8*>(vals);
    if (gid < K2PAD) {
        int tt = gid >> 7, cc = gid & 127;
        b2f[gid] = (cc < NP) ? b_lin[cc*KSZ + tt] : 0.0f;
    }
}

// ---------- kernel A v3 (unchanged): no LDS/barriers, 2 half-passes over N ----------
__global__ __launch_bounds__(256, 3)
void dyconv_gemm1(const float* __restrict__ f, const short* __restrict__ W2f,
                  const float* __restrict__ b2f, short* __restrict__ w2, int Mrows) {
    const int tid = threadIdx.x, wave = tid>>6, lane = tid&63, lg = lane>>4, li = lane&15;
    const int r0 = blockIdx.x * 64;

    int myr = r0 + wave*16 + li; if (myr > Mrows-1) myr = Mrows-1;
    const float* frow = f + (size_t)myr * HID + lg*8;
    bf16x8 a1[8];
#pragma unroll
    for (int kt = 0; kt < 8; ++kt) {
        float4 u = *reinterpret_cast<const float4*>(frow + kt*32);
        float4 v = *reinterpret_cast<const float4*>(frow + kt*32 + 4);
        short tmp[8] = {f2bf(u.x),f2bf(u.y),f2bf(u.z),f2bf(u.w),
                        f2bf(v.x),f2bf(v.y),f2bf(v.z),f2bf(v.w)};
        a1[kt] = *reinterpret_cast<bf16x8*>(tmp);
    }

    const short* Wl = W2f + (size_t)lane * 8;
    const int prow0 = wave*16 + lg*4;

#pragma unroll 1
    for (int h = 0; h < 2; ++h) {
        const int nb = h*12;
        f32x4 acc[12];
#pragma unroll
        for (int i = 0; i < 12; ++i) acc[i] = (f32x4){0.f,0.f,0.f,0.f};

        bf16x8 F0[8], F1[8];
#define LDW(FB, NTL) { _Pragma("unroll") for (int kt = 0; kt < 8; ++kt) \
    FB[kt] = *reinterpret_cast<const bf16x8*>(Wl + ((size_t)(kt*N1T + nb + (NTL)) << 9)); }
#define MM(FB, NTL) { _Pragma("unroll") for (int kt = 0; kt < 8; ++kt) \
    acc[NTL] = __builtin_amdgcn_mfma_f32_16x16x32_bf16(a1[kt], FB[kt], acc[NTL], 0,0,0); }
        LDW(F0,0)  LDW(F1,1)
        MM(F0,0)   LDW(F0,2)
        MM(F1,1)   LDW(F1,3)
        MM(F0,2)   LDW(F0,4)
        MM(F1,3)   LDW(F1,5)
        MM(F0,4)   LDW(F0,6)
        MM(F1,5)   LDW(F1,7)
        MM(F0,6)   LDW(F0,8)
        MM(F1,7)   LDW(F1,9)
        MM(F0,8)   LDW(F0,10)
        MM(F1,9)   LDW(F1,11)
        MM(F0,10)  MM(F1,11)
#undef LDW
#undef MM

#pragma unroll
        for (int r = 0; r < 4; ++r) {
            int gr = r0 + prow0 + r;
            if (gr < Mrows) {
                int bb = gr / NP, p = gr % NP;
                short* wrow = w2 + ((size_t)bb*12*NP + p)*32;
#pragma unroll
                for (int ntl = 0; ntl < 12; ++ntl) {
                    int nt = nb + ntl;
                    float bias = b2f[nt*16 + li];
                    wrow[(size_t)(nt>>1)*NP*32 + (nt&1)*16 + li] = f2bf(acc[ntl][r] + bias);
                }
            }
        }
    }
}

// ---------- kernel B v4: conv (GEMM2) + LN ----------
// scalar-pattern packed staging (conflict-light), targeted zeroing, a2n prefetch,
// launch_bounds(256,2): 112 AGPR + ~130 VGPR fits 2 waves/SIMD without spills
__global__ __launch_bounds__(256, 2)
void dyconv_conv(const float* __restrict__ k, const short* __restrict__ w2,
                 const float* __restrict__ gamma, const float* __restrict__ beta,
                 float* __restrict__ out) {
    __shared__ short kT[KT_ELEMS];     // kT[l+1][c] bf16; LN overlay after
    float* lnbuf = reinterpret_cast<float*>(kT);

    const int b = blockIdx.x, tid = threadIdx.x;
    const int wave = tid>>6, lane = tid&63, lg = lane>>4, li = lane&15;

    // zero exactly the never-staged, reachable bytes:
    // row 0 (l=-1), row 257 (l=256), c-strip [100,104) rows 1..256, guard tail
    if (tid < 52) {
        *reinterpret_cast<unsigned int*>(&kT[tid*2]) = 0u;
        *reinterpret_cast<unsigned int*>(&kT[257*PC + tid*2]) = 0u;
    }
    *reinterpret_cast<unsigned long long*>(&kT[(tid+1)*PC + 100]) = 0ull;
    if (tid < 20)
        *reinterpret_cast<unsigned long long*>(&kT[KTROWS*PC + tid*4]) = 0ull;

    // staging: 2 channels packed per b32 write; lanes walk l (stride 52 dwords, ~8-way)
    const float* kb = k + (size_t)b * (NP*HID);
    for (int u = tid; u < (NP/2)*HID; u += 256) {   // 12800 units
        int c2 = u >> 8;              // 0..49
        int l  = u & 255;
        int c  = c2*2;
        float v0 = kb[(size_t)c*HID + l];
        float v1 = kb[(size_t)(c+1)*HID + l];
        unsigned int pk = (unsigned int)(unsigned short)f2bf(v0)
                        | ((unsigned int)(unsigned short)f2bf(v1) << 16);
        *reinterpret_cast<unsigned int*>(&kT[(l+1)*PC + c]) = pk;
    }

    f32x4 acc2[7][4];
#pragma unroll
    for (int mt = 0; mt < 7; ++mt)
#pragma unroll
        for (int j = 0; j < 4; ++j) acc2[mt][j] = (f32x4){0.f,0.f,0.f,0.f};

    // hoisted clamped w2 row pointers (7 pointers, reused all 12 chunks)
    const short* wb = w2 + (size_t)b * 12 * NP * 32;
    const short* wp[7];
#pragma unroll
    for (int mt = 0; mt < 7; ++mt) {
        int p = mt*16 + li; if (p > NP-1) p = NP-1;
        wp[mt] = wb + (size_t)p*32 + lg*8;
    }

    __syncthreads();   // kT ready; no more barriers until epilogue

    bf16x8 a2[7], a2n[7];
#pragma unroll
    for (int mt = 0; mt < 7; ++mt)
        a2[mt] = *reinterpret_cast<const bf16x8*>(wp[mt]);

#pragma unroll
    for (int kc = 0; kc < 12; ++kc) {
        if (kc < 11) {
#pragma unroll
            for (int mt = 0; mt < 7; ++mt)
                a2n[mt] = *reinterpret_cast<const bf16x8*>(wp[mt] + (size_t)(kc+1)*NP*32);
        }
        int k2 = kc*32 + lg*8;
        int t  = k2 >> 7, c = k2 & 127;
#pragma unroll
        for (int j = 0; j < 4; ++j) {
            int l = (wave*4 + j)*16 + li;
            bf16x8 b2v = *reinterpret_cast<const bf16x8*>(&kT[(l + t)*PC + c]);
#pragma unroll
            for (int mt = 0; mt < 7; ++mt)
                acc2[mt][j] = __builtin_amdgcn_mfma_f32_16x16x32_bf16(
                    a2[mt], b2v, acc2[mt][j], 0,0,0);
        }
#pragma unroll
        for (int mt = 0; mt < 7; ++mt) a2[mt] = a2n[mt];
    }

    __syncthreads();   // kT reads done; overlay LN buffers

    float* psum  = lnbuf;            // [4][112][2]
    float* mrstd = lnbuf + 4*112*2;  // [112][2]
#pragma unroll
    for (int mt = 0; mt < 7; ++mt) {
#pragma unroll
        for (int r = 0; r < 4; ++r) {
            float s1 = 0.f, s2 = 0.f;
#pragma unroll
            for (int j = 0; j < 4; ++j) {
                float v = acc2[mt][j][r];
                s1 += v; s2 += v*v;
            }
#pragma unroll
            for (int m = 1; m < 16; m <<= 1) {
                s1 += __shfl_xor(s1, m, 64);
                s2 += __shfl_xor(s2, m, 64);
            }
            if (li == 0) {
                int p = mt*16 + lg*4 + r;
                psum[(wave*112 + p)*2 + 0] = s1;
                psum[(wave*112 + p)*2 + 1] = s2;
            }
        }
    }
    __syncthreads();
    if (tid < 112) {
        float S1 = 0.f, S2 = 0.f;
#pragma unroll
        for (int w2i = 0; w2i < 4; ++w2i) {
            S1 += psum[(w2i*112 + tid)*2 + 0];
            S2 += psum[(w2i*112 + tid)*2 + 1];
        }
        float mean = S1 * (1.0f/HID);
        float var  = S2 * (1.0f/HID) - mean*mean;
        mrstd[tid*2 + 0] = mean;
        mrstd[tid*2 + 1] = rsqrtf(var + 1e-5f);
    }
    __syncthreads();

    float* ob = out + (size_t)b * (NP*HID);
#pragma unroll
    for (int j = 0; j < 4; ++j) {
        int l = (wave*4 + j)*16 + li;
        float g  = gamma[l];
        float be = beta[l];
#pragma unroll
        for (int mt = 0; mt < 7; ++mt) {
#pragma unroll
            for (int r = 0; r < 4; ++r) {
                int p = mt*16 + lg*4 + r;
                if (p < NP) {
                    float mean = mrstd[p*2], rstd = mrstd[p*2 + 1];
                    ob[p*HID + l] = (acc2[mt][j][r] - mean)*rstd*g + be;
                }
            }
        }
    }
}

// ---------- fallback fused kernel (proven R1 path) if ws too small ----------
__global__ __launch_bounds__(256)
void dyconv_main(const float* __restrict__ f, const float* __restrict__ k,
                 const short* __restrict__ W2f, const float* __restrict__ b2f,
                 const float* __restrict__ gamma, const float* __restrict__ beta,
                 float* __restrict__ out) {
    __shared__ short kT[KT_ELEMS];
    __shared__ short wS[WS_ELEMS];
    float* lnbuf = reinterpret_cast<float*>(wS);
    const int b = blockIdx.x, tid = threadIdx.x;
    const int wave = tid>>6, lane = tid&63, lg = lane>>4, li = lane&15;
    for (int i = tid; i < KT_ELEMS/8; i += 256)
        reinterpret_cast<int4*>(kT)[i] = make_int4(0,0,0,0);
    __syncthreads();
    const float* kb = k + (size_t)b * (NP*HID);
    for (int idx = tid; idx < NP*HID; idx += 256) {
        int c = idx >> 8, l = idx & 255;
        kT[(l+1)*PC + c] = f2bf(kb[idx]);
    }
    const float* fb = f + (size_t)b * (NP*HID);
    const int nmy = (wave < 3) ? 2 : 1;
    bf16x8 a1[2][8];
#pragma unroll
    for (int mi = 0; mi < 2; ++mi) {
        if (mi < nmy) {
            int mt = wave + 4*mi;
            int p  = mt*16 + li; if (p > NP-1) p = NP-1;
            const float* rowp = fb + (size_t)p * HID + lg*8;
#pragma unroll
            for (int kt = 0; kt < 8; ++kt) {
                float4 u = *reinterpret_cast<const float4*>(rowp + kt*32);
                float4 v = *reinterpret_cast<const float4*>(rowp + kt*32 + 4);
                short tmp[8] = {f2bf(u.x),f2bf(u.y),f2bf(u.z),f2bf(u.w),
                                f2bf(v.x),f2bf(v.y),f2bf(v.z),f2bf(v.w)};
                a1[mi][kt] = *reinterpret_cast<bf16x8*>(tmp);
            }
        }
    }
    f32x4 acc2[7][4];
#pragma unroll
    for (int mt = 0; mt < 7; ++mt)
#pragma unroll
        for (int j = 0; j < 4; ++j) acc2[mt][j] = (f32x4){0.f,0.f,0.f,0.f};
    __syncthreads();
    for (int kc = 0; kc < 12; ++kc) {
        f32x4 acc1[2][2];
#pragma unroll
        for (int mi = 0; mi < 2; ++mi)
#pragma unroll
            for (int n = 0; n < 2; ++n) acc1[mi][n] = (f32x4){0.f,0.f,0.f,0.f};
#pragma unroll
        for (int kt = 0; kt < 8; ++kt) {
            bf16x8 b1[2];
#pragma unroll
            for (int ntl = 0; ntl < 2; ++ntl) {
                int NT = kc*2 + ntl;
                b1[ntl] = *reinterpret_cast<const bf16x8*>(
                    &W2f[(((size_t)kt*N1T + NT)*64 + lane)*8]);
            }
#pragma unroll
            for (int mi = 0; mi < 2; ++mi) {
                if (mi < nmy) {
                    acc1[mi][0] = __builtin_amdgcn_mfma_f32_16x16x32_bf16(
                        a1[mi][kt], b1[0], acc1[mi][0], 0,0,0);
                    acc1[mi][1] = __builtin_amdgcn_mfma_f32_16x16x32_bf16(
                        a1[mi][kt], b1[1], acc1[mi][1], 0,0,0);
                }
            }
        }
#pragma unroll
        for (int mi = 0; mi < 2; ++mi) {
            if (mi < nmy) {
                int mt = wave + 4*mi;
#pragma unroll
                for (int ntl = 0; ntl < 2; ++ntl) {
                    int col  = ntl*16 + li;
                    float bias = b2f[kc*32 + col];
#pragma unroll
                    for (int r = 0; r < 4; ++r) {
                        int row = mt*16 + lg*4 + r;
                        wS[row*WS_PITCH + col] = f2bf(acc1[mi][ntl][r] + bias);
                    }
                }
            }
        }
        __syncthreads();
        bf16x8 a2[7];
#pragma unroll
        for (int mt = 0; mt < 7; ++mt)
            a2[mt] = *reinterpret_cast<const bf16x8*>(&wS[(mt*16 + li)*WS_PITCH + lg*8]);
        int k2 = kc*32 + lg*8;
        int t  = k2 >> 7, c = k2 & 127;
#pragma unroll
        for (int j = 0; j < 4; ++j) {
            int l = (wave*4 + j)*16 + li;
            bf16x8 b2v = *reinterpret_cast<const bf16x8*>(&kT[(l + t)*PC + c]);
#pragma unroll
            for (int mt = 0; mt < 7; ++mt)
                acc2[mt][j] = __builtin_amdgcn_mfma_f32_16x16x32_bf16(
                    a2[mt], b2v, acc2[mt][j], 0,0,0);
        }
        __syncthreads();
    }
    float* psum  = lnbuf;
    float* mrstd = lnbuf + 4*112*2;
#pragma unroll
    for (int mt = 0; mt < 7; ++mt) {
#pragma unroll
        for (int r = 0; r < 4; ++r) {
            float s1 = 0.f, s2 = 0.f;
#pragma unroll
            for (int j = 0; j < 4; ++j) {
                float v = acc2[mt][j][r];
                s1 += v; s2 += v*v;
            }
#pragma unroll
            for (int m = 1; m < 16; m <<= 1) {
                s1 += __shfl_xor(s1, m, 64);
                s2 += __shfl_xor(s2, m, 64);
            }
            if (li == 0) {
                int p = mt*16 + lg*4 + r;
                psum[(wave*112 + p)*2 + 0] = s1;
                psum[(wave*112 + p)*2 + 1] = s2;
            }
        }
    }
    __syncthreads();
    if (tid < 112) {
        float S1 = 0.f, S2 = 0.f;
#pragma unroll
        for (int w2i = 0; w2i < 4; ++w2i) {
            S1 += psum[(w2i*112 + tid)*2 + 0];
            S2 += psum[(w2i*112 + tid)*2 + 1];
        }
        float mean = S1 * (1.0f/HID);
        float var  = S2 * (1.0f/HID) - mean*mean;
        mrstd[tid*2 + 0] = mean;
        mrstd[tid*2 + 1] = rsqrtf(var + 1e-5f);
    }
    __syncthreads();
    float* ob = out + (size_t)b * (NP*HID);
#pragma unroll
    for (int j = 0; j < 4; ++j) {
        int l = (wave*4 + j)*16 + li;
        float g  = gamma[l];
        float be = beta[l];
#pragma unroll
        for (int mt = 0; mt < 7; ++mt) {
#pragma unroll
            for (int r = 0; r < 4; ++r) {
                int p = mt*16 + lg*4 + r;
                if (p < NP) {
                    float mean = mrstd[p*2], rstd = mrstd[p*2 + 1];
                    ob[p*HID + l] = (acc2[mt][j][r] - mean)*rstd*g + be;
                }
            }
        }
    }
}

extern "C" void kernel_launch(void* const* d_in, const int* in_sizes, int n_in,
                              void* d_out, int out_size, void* d_ws, size_t ws_size,
                              hipStream_t stream) {
    const float* f     = (const float*)d_in[0];
    const float* k     = (const float*)d_in[1];
    const float* W_lin = (const float*)d_in[2];
    const float* b_lin = (const float*)d_in[3];
    const float* gamma = (const float*)d_in[4];
    const float* beta  = (const float*)d_in[5];
    float* out = (float*)d_out;

    short* W2f = (short*)d_ws;                                   // 196608 B
    float* b2f = (float*)((char*)d_ws + 196608);                 // 1536 B
    const size_t off_w2 = 198144;
    const int B = in_sizes[0] / (NP*HID);
    const int Mrows = B * NP;
    const size_t need = off_w2 + (size_t)B * 12 * NP * 32 * 2;   // ~78.8 MB @ B=1024

    dyconv_prep<<<48, 256, 0, stream>>>(W_lin, b_lin, W2f, b2f);

    if (ws_size >= need) {
        short* w2 = (short*)((char*)d_ws + off_w2);
        dyconv_gemm1<<<(Mrows + 63)/64, 256, 0, stream>>>(f, W2f, b2f, w2, Mrows);
        dyconv_conv<<<B, 256, 0, stream>>>(k, w2, gamma, beta, out);
    } else {
        dyconv_main<<<B, 256, 0, stream>>>(f, k, W2f, b2f, gamma, beta, out);
    }
}